// Round 10
// baseline (142.210 us; speedup 1.0000x reference)
//
#include <hip/hip_runtime.h>
#include <hip/hip_bf16.h>

#define NB 4
#define NH 4
#define TT 2048
#define DKK 64
#define NF 256
#define QT 16

typedef __attribute__((ext_vector_type(8))) short bf16x8;
typedef __attribute__((ext_vector_type(4))) short s16x4;
typedef __attribute__((ext_vector_type(4))) float f32x4;
typedef __hip_bfloat16 bf16;

__device__ __forceinline__ short f2bs(float f) {
    bf16 h = __float2bfloat16(f);
    return *reinterpret_cast<short*>(&h);
}
__device__ __forceinline__ float b2f(short s) {
    return __uint_as_float(((unsigned)(unsigned short)s) << 16);
}
__device__ __forceinline__ float wave_sum(float v) {
    #pragma unroll
    for (int off = 1; off < 64; off <<= 1) v += __shfl_xor(v, off);
    return v;
}
// barrier that orders LDS only -- does NOT drain outstanding global stores
__device__ __forceinline__ void lds_barrier() {
    asm volatile("s_waitcnt lgkmcnt(0)" ::: "memory");
    __builtin_amdgcn_s_barrier();
    __builtin_amdgcn_sched_barrier(0);
}

// ------- Kernel 0: W fp32 -> bf16, and mask -> bitmask (block 192) ----------
__global__ __launch_bounds__(256)
void wcvt_kernel(const float* __restrict__ Wq, const float* __restrict__ Wk,
                 const float* __restrict__ Wv, const int* __restrict__ mask,
                 bf16* __restrict__ Wb, unsigned* __restrict__ mbits)
{
    if (blockIdx.x == 192) {   // pack mask: 4 batches x 2048 cols -> 256 words
        int t = threadIdx.x;
        const int* mp = mask + t * 32;
        unsigned m = 0;
        #pragma unroll
        for (int j = 0; j < 32; ++j) m |= (mp[j] != 0 ? 1u : 0u) << j;
        mbits[t] = m;
        return;
    }
    int gid = (blockIdx.x * 256 + threadIdx.x) * 4;   // 192 blocks -> 196608 elems
    const float* src;
    int m = gid >> 16, off = gid & 65535;
    src = (m == 0) ? Wq : (m == 1) ? Wk : Wv;
    float4 v = *(const float4*)(src + off);
    s16x4 o = { f2bs(v.x), f2bs(v.y), f2bs(v.z), f2bs(v.w) };
    *(s16x4*)((short*)Wb + gid) = o;
}

// ---------------- Kernel 1: MFMA QKV + bias + L2 norm -> fragment layouts ---
// Outputs (all bf16, per bh stride 16384 x 16B):
//  qB[bh][qt][j][lane][8] = q[qt*16+(lane&15)][j*32+(lane>>4)*8+e]
//  kA[bh][kt][j][lane][8] = k[kt*16+(lane&15)][j*32+(lane>>4)*8+e]
//  vB[bh][kc][ds][lane][8] = V[kc*32+(lane>>4)*8+e][ds*16+(lane&15)]
__global__ __launch_bounds__(256, 4)
void qkv_kernel(const float* __restrict__ query, const float* __restrict__ key,
                const float* __restrict__ value, const bf16* __restrict__ Wb,
                const float* __restrict__ bq, const float* __restrict__ bk,
                const float* __restrict__ bv,
                bf16* __restrict__ qB, bf16* __restrict__ kA, bf16* __restrict__ vB)
{
    __shared__ char Xq[8192], Xk[8192], Xv[8192];   // [16][256] bf16, XOR-swizzled
    __shared__ char bounce[24576];                  // qBs 8K | kAs 8K | vBs 8K
    const int tid = threadIdx.x;
    const int bt0 = blockIdx.x * 16;
    const int b0 = bt0 >> 11, t0 = bt0 & (TT - 1);

    {   // stage X bf16 (swizzle: byte ^= (row&7)<<4)
        int row = tid >> 4, c0 = (tid & 15) * 16;
        int swr = (row & 7) << 4;
        const float* qs = query + (size_t)(bt0 + row) * NF + c0;
        const float* ks = key   + (size_t)(bt0 + row) * NF + c0;
        const float* vs = value + (size_t)(bt0 + row) * NF + c0;
        #pragma unroll
        for (int j = 0; j < 4; ++j) {
            float4 a = *(const float4*)(qs + j * 4);
            float4 b = *(const float4*)(ks + j * 4);
            float4 c = *(const float4*)(vs + j * 4);
            int byt = (row * 512 + c0 * 2 + j * 8) ^ swr;
            *(s16x4*)(Xq + byt) = (s16x4){ f2bs(a.x), f2bs(a.y), f2bs(a.z), f2bs(a.w) };
            *(s16x4*)(Xk + byt) = (s16x4){ f2bs(b.x), f2bs(b.y), f2bs(b.z), f2bs(b.w) };
            *(s16x4*)(Xv + byt) = (s16x4){ f2bs(c.x), f2bs(c.y), f2bs(c.z), f2bs(c.w) };
        }
    }
    __syncthreads();

    const int lane = tid & 63;
    const int w = tid >> 6;            // wave = head
    const int l15 = lane & 15;
    const int g = lane >> 4;
    const int swl = (l15 & 7) << 4;

    f32x4 qa[4], ka[4], va[4];
    #pragma unroll
    for (int ct = 0; ct < 4; ++ct) {
        qa[ct] = (f32x4){0.f,0.f,0.f,0.f};
        ka[ct] = (f32x4){0.f,0.f,0.f,0.f};
        va[ct] = (f32x4){0.f,0.f,0.f,0.f};
    }
    const bf16* Wqb = Wb;
    const bf16* Wkb = Wb + 65536;
    const bf16* Wvb = Wb + 131072;

    #pragma unroll
    for (int kt = 0; kt < 8; ++kt) {
        int byt = (l15 * 512 + kt * 64 + g * 16) ^ swl;
        bf16x8 xq = *(const bf16x8*)(Xq + byt);
        bf16x8 xk = *(const bf16x8*)(Xk + byt);
        bf16x8 xv = *(const bf16x8*)(Xv + byt);
        #pragma unroll
        for (int ct = 0; ct < 4; ++ct) {
            size_t wo = (size_t)(w * 64 + ct * 16 + l15) * NF + kt * 32 + g * 8;
            bf16x8 aq = *(const bf16x8*)(Wqb + wo);
            bf16x8 ak = *(const bf16x8*)(Wkb + wo);
            bf16x8 av = *(const bf16x8*)(Wvb + wo);
            qa[ct] = __builtin_amdgcn_mfma_f32_16x16x32_bf16(aq, xq, qa[ct], 0, 0, 0);
            ka[ct] = __builtin_amdgcn_mfma_f32_16x16x32_bf16(ak, xk, ka[ct], 0, 0, 0);
            va[ct] = __builtin_amdgcn_mfma_f32_16x16x32_bf16(av, xv, va[ct], 0, 0, 0);
        }
    }

    // bias (fp32) + norms per (token=l15, head=w); lane holds o=ct*16+g*4+p
    float qv[4][4], kv[4][4], vv[4][4];
    float sq = 0.f, sk = 0.f;
    #pragma unroll
    for (int ct = 0; ct < 4; ++ct) {
        float4 b4q = *(const float4*)(bq + w * 64 + ct * 16 + g * 4);
        float4 b4k = *(const float4*)(bk + w * 64 + ct * 16 + g * 4);
        float4 b4v = *(const float4*)(bv + w * 64 + ct * 16 + g * 4);
        #pragma unroll
        for (int p = 0; p < 4; ++p) {
            float bqp = (p == 0) ? b4q.x : (p == 1) ? b4q.y : (p == 2) ? b4q.z : b4q.w;
            float bkp = (p == 0) ? b4k.x : (p == 1) ? b4k.y : (p == 2) ? b4k.z : b4k.w;
            float bvp = (p == 0) ? b4v.x : (p == 1) ? b4v.y : (p == 2) ? b4v.z : b4v.w;
            qv[ct][p] = qa[ct][p] + bqp;
            kv[ct][p] = ka[ct][p] + bkp;
            vv[ct][p] = va[ct][p] + bvp;
            sq = __builtin_fmaf(qv[ct][p], qv[ct][p], sq);
            sk = __builtin_fmaf(kv[ct][p], kv[ct][p], sk);
        }
    }
    sq += __shfl_xor(sq, 16); sq += __shfl_xor(sq, 32);
    sk += __shfl_xor(sk, 16); sk += __shfl_xor(sk, 32);
    float nq = rsqrtf(sq) * 0.125f;    // fold 1/sqrt(dk)
    float nk = rsqrtf(sk);

    __syncthreads();
    // scatter into bounce (LDS): q/k packed s16x4, v per-element
    #pragma unroll
    for (int ct = 0; ct < 4; ++ct) {
        int d5 = (ct & 1) * 16 + g * 4;       // p=0; (d5&7) in {0,4} so p=0..3 same group
        int qb = w * 2048 + (ct >> 1) * 1024 + (d5 >> 3) * 256 + l15 * 16 + (d5 & 7) * 2;
        s16x4 oq = { f2bs(qv[ct][0]*nq), f2bs(qv[ct][1]*nq), f2bs(qv[ct][2]*nq), f2bs(qv[ct][3]*nq) };
        s16x4 ok = { f2bs(kv[ct][0]*nk), f2bs(kv[ct][1]*nk), f2bs(kv[ct][2]*nk), f2bs(kv[ct][3]*nk) };
        *(s16x4*)(bounce + qb)        = oq;
        *(s16x4*)(bounce + qb + 8192) = ok;
        #pragma unroll
        for (int p = 0; p < 4; ++p) {
            int vb = 16384 + w * 2048 + ct * 512 + (l15 >> 3) * 256 + (g * 4 + p) * 16 + (l15 & 7) * 2;
            *(short*)(bounce + vb) = f2bs(vv[ct][p]);
        }
    }
    __syncthreads();

    const int qt = t0 >> 4;                 // also kt
    const int kc = t0 >> 5, h16 = (t0 >> 4) & 1;
    for (int seg = tid; seg < 1536; seg += 256) {
        int byt = seg * 16;
        const char* src = bounce + byt;
        bf16* dst;
        if (byt < 8192) {
            int wh = byt >> 11, off = byt & 2047;
            dst = qB + (((size_t)(b0 * NH + wh)) * 128 + qt) * 1024 + off / 2;
        } else if (byt < 16384) {
            int r = byt - 8192;
            int wh = r >> 11, off = r & 2047;
            dst = kA + (((size_t)(b0 * NH + wh)) * 128 + qt) * 1024 + off / 2;
        } else {
            int r = byt - 16384;
            int wh = r >> 11, ct = (r >> 9) & 3, off = r & 511;
            dst = vB + ((((size_t)(b0 * NH + wh)) * 64 + kc) * 4 + ct) * 512 + h16 * 256 + off / 2;
        }
        *(bf16x8*)dst = *(const bf16x8*)src;
    }
}

// ------- Kernel 2: MFMA scores + wave-local sparsemax + PV + deferred stores
// grid: 2048 blocks (XCD-swizzled), 512 threads = 8 waves.
// Phase 1: scores -> S_s (bf16, swizzled). Phase 2: wave-local Michelot.
// Phase 3: P bf16 -> S_s in place (LDS only). Phase 4: PV + x store.
// Phase 5: attn dump from S_s (no vmem-load waits after -> stores drain at end).
__global__ __launch_bounds__(512, 4)
void attn_kernel(const bf16* __restrict__ qB, const bf16* __restrict__ kA,
                 const bf16* __restrict__ vB, const unsigned* __restrict__ mbits,
                 float* __restrict__ attn, float* __restrict__ xout)
{
    __shared__ short S_s[16 * 2048];          // 64 KB, swizzle: byte ^= (row&7)<<4
    __shared__ float4 xpart[4][64];           // 4 KB
    const int tid = threadIdx.x;
    const int lane = tid & 63;
    const int w = tid >> 6;                   // 0..7
    const int l15 = lane & 15;
    const int g = lane >> 4;                  // 0..3
    // XCD swizzle: 2048 blocks, 8 XCDs -> each XCD owns 2 consecutive bh
    const int swz = (blockIdx.x & 7) * 256 + (blockIdx.x >> 3);
    const int bh = swz >> 7;
    const int qt = swz & 127;
    const int q0 = qt * QT;
    const int b_ = bh >> 2, h_ = bh & 3;

    const size_t fb = (size_t)bh * 16384;     // 16B-unit stride per bh
    const bf16x8* qBv = (const bf16x8*)qB + fb + (size_t)qt * 128;
    const bf16x8* kAv = (const bf16x8*)kA + fb;
    const bf16x8* vBv = (const bf16x8*)vB + fb;

    // mask bits for this wave's 256-col stripe: words w*8..w*8+7
    unsigned mreg[8];
    {
        const unsigned* mwp = mbits + b_ * 64 + w * 8;
        #pragma unroll
        for (int i = 0; i < 8; ++i) mreg[i] = mwp[i];
    }

    bf16x8 qf0 = qBv[lane];
    bf16x8 qf1 = qBv[64 + lane];

    f32x4 acc[16];
    #pragma unroll
    for (int t = 0; t < 16; ++t) acc[t] = (f32x4){0.f, 0.f, 0.f, 0.f};

    #pragma unroll
    for (int t = 0; t < 16; ++t) {
        int kt = w * 16 + t;
        bf16x8 kf0 = kAv[(kt * 2 + 0) * 64 + lane];
        bf16x8 kf1 = kAv[(kt * 2 + 1) * 64 + lane];
        acc[t] = __builtin_amdgcn_mfma_f32_16x16x32_bf16(kf0, qf0, acc[t], 0, 0, 0);
        acc[t] = __builtin_amdgcn_mfma_f32_16x16x32_bf16(kf1, qf1, acc[t], 0, 0, 0);
    }

    // fold mask (bit test), store masked scores bf16 into swizzled LDS
    const short NEGB = (short)0xFF7F;         // bf16 -3.39e38
    char* prow = (char*)S_s + l15 * 4096;
    const int sw = (l15 & 7) << 4;
    #pragma unroll
    for (int t = 0; t < 16; ++t) {
        unsigned bits = mreg[t >> 1] >> (((t & 1) << 4) + (g << 2));
        s16x4 sb;
        sb[0] = (bits & 1) ? f2bs(acc[t][0]) : NEGB;
        sb[1] = (bits & 2) ? f2bs(acc[t][1]) : NEGB;
        sb[2] = (bits & 4) ? f2bs(acc[t][2]) : NEGB;
        sb[3] = (bits & 8) ? f2bs(acc[t][3]) : NEGB;
        *(s16x4*)(prow + ((w * 512 + t * 32 + g * 8) ^ sw)) = sb;
    }
    lds_barrier();

    // ---- phase 2: wave-local sparsemax on rows 2w, 2w+1 ----
    const int r0 = 2 * w;
    float va[2][32];
    #pragma unroll
    for (int h = 0; h < 2; ++h) {
        const char* sr = (const char*)S_s + (r0 + h) * 4096;
        int swr = ((r0 + h) & 7) << 4;
        #pragma unroll
        for (int jj = 0; jj < 8; ++jj) {
            s16x4 p4 = *(const s16x4*)(sr + ((jj * 512 + lane * 8) ^ swr));
            va[h][jj * 4 + 0] = b2f(p4[0]);
            va[h][jj * 4 + 1] = b2f(p4[1]);
            va[h][jj * 4 + 2] = b2f(p4[2]);
            va[h][jj * 4 + 3] = b2f(p4[3]);
        }
    }

    float tau[2];
    #pragma unroll
    for (int h = 0; h < 2; ++h) {
        float S = 0.f, C = 0.f, Qs = 0.f;
        #pragma unroll
        for (int i = 0; i < 32; ++i) {
            float v = va[h][i];
            bool un = v > -1.0e30f;
            float sv = un ? v : 0.f;
            S += sv;
            C += un ? 1.f : 0.f;
            Qs = __builtin_fmaf(sv, sv, Qs);
        }
        S = wave_sum(S); C = wave_sum(C); Qs = wave_sum(Qs);
        float tu, prevC;
        bool done;
        if (C < 0.5f) { tu = 3.0e38f; done = true; prevC = 0.f; }
        else {
            float mu = S / C;
            float var = Qs / C - mu * mu;
            var = var > 0.f ? var : 0.f;
            tu = mu + 1.7f * __builtin_sqrtf(var);   // warm start
            prevC = -1.f;
            done = false;
        }
        for (int it = 0; it < 64 && !done; ++it) {
            float S2 = 0.f, C2 = 0.f;
            #pragma unroll
            for (int i = 0; i < 32; ++i) {
                float v = va[h][i];
                bool in = v > tu;
                S2 += in ? v : 0.f;
                C2 += in ? 1.f : 0.f;
            }
            S2 = wave_sum(S2); C2 = wave_sum(C2);
            if (C2 == prevC) done = true;
            else if (C2 < 0.5f) { tu = (S - 1.f) / C; prevC = -1.f; }  // overshoot restart
            else { tu = (S2 - 1.f) / C2; prevC = C2; }
        }
        tau[h] = tu;
    }

    // ---- phase 3: P = relu(s - tau) bf16 back into LDS (wave-private rows) ----
    #pragma unroll
    for (int h = 0; h < 2; ++h) {
        char* sr = (char*)S_s + (r0 + h) * 4096;
        int swr = ((r0 + h) & 7) << 4;
        float tu = tau[h];
        #pragma unroll
        for (int jj = 0; jj < 8; ++jj) {
            s16x4 pb4;
            #pragma unroll
            for (int e = 0; e < 4; ++e) {
                float a = va[h][jj * 4 + e] - tu;
                a = a > 0.f ? a : 0.f;
                pb4[e] = f2bs(a);
            }
            *(s16x4*)(sr + ((jj * 512 + lane * 8) ^ swr)) = pb4;
        }
    }
    lds_barrier();

    // ---- phase 4: fused PV: wave w -> d-slice ds=(w&3)*16, K-half kh=w>>2 ----
    const int ds = w & 3;
    const int kh = w >> 2;
    f32x4 xacc = (f32x4){0.f, 0.f, 0.f, 0.f};
    __builtin_amdgcn_s_setprio(1);
    #pragma unroll 8
    for (int kcl = 0; kcl < 32; ++kcl) {
        int kc = kh * 32 + kcl;
        bf16x8 af = *(const bf16x8*)(prow + ((kh * 2048 + kcl * 64 + g * 16) ^ sw));
        bf16x8 bfr = vBv[(kc * 4 + ds) * 64 + lane];
        xacc = __builtin_amdgcn_mfma_f32_16x16x32_bf16(af, bfr, xacc, 0, 0, 0);
    }
    __builtin_amdgcn_s_setprio(0);
    if (w >= 4) xpart[w - 4][lane] = make_float4(xacc[0], xacc[1], xacc[2], xacc[3]);
    lds_barrier();
    if (w < 4) {
        float4 xp4 = xpart[w][lane];
        xacc[0] += xp4.x; xacc[1] += xp4.y; xacc[2] += xp4.z; xacc[3] += xp4.w;
        float* xp = xout + ((size_t)b_ * TT + q0 + g * 4) * NF + h_ * DKK + ds * 16 + l15;
        #pragma unroll
        for (int p = 0; p < 4; ++p)
            __builtin_nontemporal_store(xacc[p], xp + p * NF);
    }

    // ---- phase 5: attn dump from S_s (P) -- last vmem ops, drain at endpgm ----
    {
        int row = 2 * w + (lane >> 5);          // 0..15
        int c0 = (lane & 31) * 4;
        const char* pr = (const char*)S_s + row * 4096;
        int swr = (row & 7) << 4;
        float* ar = attn + ((size_t)bh * TT + q0 + row) * TT;
        #pragma unroll
        for (int i = 0; i < 16; ++i) {
            int c = c0 + i * 128;
            uint2 pk = *(const uint2*)(pr + ((c * 2) ^ swr));  // 4 bf16
            f32x4 o;
            o[0] = __uint_as_float(pk.x << 16);
            o[1] = __uint_as_float(pk.x & 0xffff0000u);
            o[2] = __uint_as_float(pk.y << 16);
            o[3] = __uint_as_float(pk.y & 0xffff0000u);
            __builtin_nontemporal_store(o, (f32x4*)(ar + c));
        }
    }
}

extern "C" void kernel_launch(void* const* d_in, const int* in_sizes, int n_in,
                              void* d_out, int out_size, void* d_ws, size_t ws_size,
                              hipStream_t stream) {
    const float* query = (const float*)d_in[0];
    const float* key   = (const float*)d_in[1];
    const float* value = (const float*)d_in[2];
    const int*   mask  = (const int*)d_in[3];
    const float* Wq = (const float*)d_in[4];
    const float* bq = (const float*)d_in[5];
    const float* Wk = (const float*)d_in[6];
    const float* bk = (const float*)d_in[7];
    const float* Wv = (const float*)d_in[8];
    const float* bv = (const float*)d_in[9];

    float* attn = (float*)d_out;                                 // (B,H,T,T)
    float* x    = (float*)d_out + (size_t)NB * NH * TT * TT;     // (B,T,NF)

    const size_t FRAG = (size_t)NB * NH * 16384 * 8;             // 2,097,152 bf16 each
    bf16* Wb = (bf16*)d_ws;                  // 384 KB
    bf16* qB = Wb + 3 * 65536;               // 4 MB
    bf16* kA = qB + FRAG;                    // 4 MB
    bf16* vB = kA + FRAG;                    // 4 MB
    unsigned* mbits = (unsigned*)(vB + FRAG);// 1 KB

    wcvt_kernel<<<dim3(193), dim3(256), 0, stream>>>(Wq, Wk, Wv, mask, Wb, mbits);
    qkv_kernel<<<dim3(NB * TT / 16), dim3(256), 0, stream>>>(
        query, key, value, Wb, bq, bk, bv, qB, kA, vB);
    attn_kernel<<<dim3(NB * NH * (TT / QT)), dim3(512), 0, stream>>>(
        qB, kA, vB, mbits, attn, x);
}

// Round 11
// 127.139 us; speedup vs baseline: 1.1185x; 1.1185x over previous
//
#include <hip/hip_runtime.h>
#include <hip/hip_bf16.h>

#define NB 4
#define NH 4
#define TT 2048
#define DKK 64
#define NF 256
#define QT 16

typedef __attribute__((ext_vector_type(8))) short bf16x8;
typedef __attribute__((ext_vector_type(4))) short s16x4;
typedef __attribute__((ext_vector_type(4))) float f32x4;
typedef __hip_bfloat16 bf16;

__device__ __forceinline__ short f2bs(float f) {
    bf16 h = __float2bfloat16(f);
    return *reinterpret_cast<short*>(&h);
}
__device__ __forceinline__ float b2f(short s) {
    return __uint_as_float(((unsigned)(unsigned short)s) << 16);
}
__device__ __forceinline__ float wave_sum(float v) {
    #pragma unroll
    for (int off = 1; off < 64; off <<= 1) v += __shfl_xor(v, off);
    return v;
}
// barrier that orders LDS only -- does NOT drain outstanding global stores
__device__ __forceinline__ void lds_barrier() {
    asm volatile("s_waitcnt lgkmcnt(0)" ::: "memory");
    __builtin_amdgcn_s_barrier();
    __builtin_amdgcn_sched_barrier(0);
}

// ------- Kernel 0: W fp32 -> bf16, and mask -> bitmask (block 192) ----------
__global__ __launch_bounds__(256)
void wcvt_kernel(const float* __restrict__ Wq, const float* __restrict__ Wk,
                 const float* __restrict__ Wv, const int* __restrict__ mask,
                 bf16* __restrict__ Wb, unsigned* __restrict__ mbits)
{
    if (blockIdx.x == 192) {   // pack mask: 4 batches x 2048 cols -> 256 words
        int t = threadIdx.x;
        const int* mp = mask + t * 32;
        unsigned m = 0;
        #pragma unroll
        for (int j = 0; j < 32; ++j) m |= (mp[j] != 0 ? 1u : 0u) << j;
        mbits[t] = m;
        return;
    }
    int gid = (blockIdx.x * 256 + threadIdx.x) * 4;   // 192 blocks -> 196608 elems
    const float* src;
    int m = gid >> 16, off = gid & 65535;
    src = (m == 0) ? Wq : (m == 1) ? Wk : Wv;
    float4 v = *(const float4*)(src + off);
    s16x4 o = { f2bs(v.x), f2bs(v.y), f2bs(v.z), f2bs(v.w) };
    *(s16x4*)((short*)Wb + gid) = o;
}

// ---------------- Kernel 1: MFMA QKV + bias + L2 norm -> fragment layouts ---
// Outputs (all bf16, per bh stride 16384 x 16B):
//  qB[bh][qt][j][lane][8] = q[qt*16+(lane&15)][j*32+(lane>>4)*8+e]
//  kA[bh][kt][j][lane][8] = k[kt*16+(lane&15)][j*32+(lane>>4)*8+e]
//  vB[bh][kc][ds][lane][8] = V[kc*32+(lane>>4)*8+e][ds*16+(lane&15)]
__global__ __launch_bounds__(256, 4)
void qkv_kernel(const float* __restrict__ query, const float* __restrict__ key,
                const float* __restrict__ value, const bf16* __restrict__ Wb,
                const float* __restrict__ bq, const float* __restrict__ bk,
                const float* __restrict__ bv,
                bf16* __restrict__ qB, bf16* __restrict__ kA, bf16* __restrict__ vB)
{
    __shared__ char Xq[8192], Xk[8192], Xv[8192];   // [16][256] bf16, XOR-swizzled
    __shared__ char bounce[24576];                  // qBs 8K | kAs 8K | vBs 8K
    const int tid = threadIdx.x;
    const int bt0 = blockIdx.x * 16;
    const int b0 = bt0 >> 11, t0 = bt0 & (TT - 1);

    {   // stage X bf16 (swizzle: byte ^= (row&7)<<4)
        int row = tid >> 4, c0 = (tid & 15) * 16;
        int swr = (row & 7) << 4;
        const float* qs = query + (size_t)(bt0 + row) * NF + c0;
        const float* ks = key   + (size_t)(bt0 + row) * NF + c0;
        const float* vs = value + (size_t)(bt0 + row) * NF + c0;
        #pragma unroll
        for (int j = 0; j < 4; ++j) {
            float4 a = *(const float4*)(qs + j * 4);
            float4 b = *(const float4*)(ks + j * 4);
            float4 c = *(const float4*)(vs + j * 4);
            int byt = (row * 512 + c0 * 2 + j * 8) ^ swr;
            *(s16x4*)(Xq + byt) = (s16x4){ f2bs(a.x), f2bs(a.y), f2bs(a.z), f2bs(a.w) };
            *(s16x4*)(Xk + byt) = (s16x4){ f2bs(b.x), f2bs(b.y), f2bs(b.z), f2bs(b.w) };
            *(s16x4*)(Xv + byt) = (s16x4){ f2bs(c.x), f2bs(c.y), f2bs(c.z), f2bs(c.w) };
        }
    }
    __syncthreads();

    const int lane = tid & 63;
    const int w = tid >> 6;            // wave = head
    const int l15 = lane & 15;
    const int g = lane >> 4;
    const int swl = (l15 & 7) << 4;

    f32x4 qa[4], ka[4], va[4];
    #pragma unroll
    for (int ct = 0; ct < 4; ++ct) {
        qa[ct] = (f32x4){0.f,0.f,0.f,0.f};
        ka[ct] = (f32x4){0.f,0.f,0.f,0.f};
        va[ct] = (f32x4){0.f,0.f,0.f,0.f};
    }
    const bf16* Wqb = Wb;
    const bf16* Wkb = Wb + 65536;
    const bf16* Wvb = Wb + 131072;

    #pragma unroll
    for (int kt = 0; kt < 8; ++kt) {
        int byt = (l15 * 512 + kt * 64 + g * 16) ^ swl;
        bf16x8 xq = *(const bf16x8*)(Xq + byt);
        bf16x8 xk = *(const bf16x8*)(Xk + byt);
        bf16x8 xv = *(const bf16x8*)(Xv + byt);
        #pragma unroll
        for (int ct = 0; ct < 4; ++ct) {
            size_t wo = (size_t)(w * 64 + ct * 16 + l15) * NF + kt * 32 + g * 8;
            bf16x8 aq = *(const bf16x8*)(Wqb + wo);
            bf16x8 ak = *(const bf16x8*)(Wkb + wo);
            bf16x8 av = *(const bf16x8*)(Wvb + wo);
            qa[ct] = __builtin_amdgcn_mfma_f32_16x16x32_bf16(aq, xq, qa[ct], 0, 0, 0);
            ka[ct] = __builtin_amdgcn_mfma_f32_16x16x32_bf16(ak, xk, ka[ct], 0, 0, 0);
            va[ct] = __builtin_amdgcn_mfma_f32_16x16x32_bf16(av, xv, va[ct], 0, 0, 0);
        }
    }

    // bias (fp32) + norms per (token=l15, head=w); lane holds o=ct*16+g*4+p
    float qv[4][4], kv[4][4], vv[4][4];
    float sq = 0.f, sk = 0.f;
    #pragma unroll
    for (int ct = 0; ct < 4; ++ct) {
        float4 b4q = *(const float4*)(bq + w * 64 + ct * 16 + g * 4);
        float4 b4k = *(const float4*)(bk + w * 64 + ct * 16 + g * 4);
        float4 b4v = *(const float4*)(bv + w * 64 + ct * 16 + g * 4);
        #pragma unroll
        for (int p = 0; p < 4; ++p) {
            float bqp = (p == 0) ? b4q.x : (p == 1) ? b4q.y : (p == 2) ? b4q.z : b4q.w;
            float bkp = (p == 0) ? b4k.x : (p == 1) ? b4k.y : (p == 2) ? b4k.z : b4k.w;
            float bvp = (p == 0) ? b4v.x : (p == 1) ? b4v.y : (p == 2) ? b4v.z : b4v.w;
            qv[ct][p] = qa[ct][p] + bqp;
            kv[ct][p] = ka[ct][p] + bkp;
            vv[ct][p] = va[ct][p] + bvp;
            sq = __builtin_fmaf(qv[ct][p], qv[ct][p], sq);
            sk = __builtin_fmaf(kv[ct][p], kv[ct][p], sk);
        }
    }
    sq += __shfl_xor(sq, 16); sq += __shfl_xor(sq, 32);
    sk += __shfl_xor(sk, 16); sk += __shfl_xor(sk, 32);
    float nq = rsqrtf(sq) * 0.125f;    // fold 1/sqrt(dk)
    float nk = rsqrtf(sk);

    __syncthreads();
    // scatter into bounce (LDS): q/k packed s16x4, v per-element
    #pragma unroll
    for (int ct = 0; ct < 4; ++ct) {
        int d5 = (ct & 1) * 16 + g * 4;
        int qb = w * 2048 + (ct >> 1) * 1024 + (d5 >> 3) * 256 + l15 * 16 + (d5 & 7) * 2;
        s16x4 oq = { f2bs(qv[ct][0]*nq), f2bs(qv[ct][1]*nq), f2bs(qv[ct][2]*nq), f2bs(qv[ct][3]*nq) };
        s16x4 ok = { f2bs(kv[ct][0]*nk), f2bs(kv[ct][1]*nk), f2bs(kv[ct][2]*nk), f2bs(kv[ct][3]*nk) };
        *(s16x4*)(bounce + qb)        = oq;
        *(s16x4*)(bounce + qb + 8192) = ok;
        #pragma unroll
        for (int p = 0; p < 4; ++p) {
            int vb = 16384 + w * 2048 + ct * 512 + (l15 >> 3) * 256 + (g * 4 + p) * 16 + (l15 & 7) * 2;
            *(short*)(bounce + vb) = f2bs(vv[ct][p]);
        }
    }
    __syncthreads();

    const int qt = t0 >> 4;                 // also kt
    const int kc = t0 >> 5, h16 = (t0 >> 4) & 1;
    for (int seg = tid; seg < 1536; seg += 256) {
        int byt = seg * 16;
        const char* src = bounce + byt;
        bf16* dst;
        if (byt < 8192) {
            int wh = byt >> 11, off = byt & 2047;
            dst = qB + (((size_t)(b0 * NH + wh)) * 128 + qt) * 1024 + off / 2;
        } else if (byt < 16384) {
            int r = byt - 8192;
            int wh = r >> 11, off = r & 2047;
            dst = kA + (((size_t)(b0 * NH + wh)) * 128 + qt) * 1024 + off / 2;
        } else {
            int r = byt - 16384;
            int wh = r >> 11, ct = (r >> 9) & 3, off = r & 511;
            dst = vB + ((((size_t)(b0 * NH + wh)) * 64 + kc) * 4 + ct) * 512 + h16 * 256 + off / 2;
        }
        *(bf16x8*)dst = *(const bf16x8*)src;
    }
}

// ------- Kernel 2: MFMA scores + per-row (sparsemax -> store) + fused PV ----
// grid: 2048 blocks (XCD-swizzled), 512 threads = 8 waves.
__global__ __launch_bounds__(512, 4)
void attn_kernel(const bf16* __restrict__ qB, const bf16* __restrict__ kA,
                 const bf16* __restrict__ vB, const unsigned* __restrict__ mbits,
                 float* __restrict__ attn, float* __restrict__ xout)
{
    __shared__ short S_s[16 * 2048];          // 64 KB, swizzle: byte ^= (row&7)<<4
    __shared__ float4 xpart[4][64];           // 4 KB
    const int tid = threadIdx.x;
    const int lane = tid & 63;
    const int w = tid >> 6;                   // 0..7
    const int l15 = lane & 15;
    const int g = lane >> 4;                  // 0..3
    // XCD swizzle: 2048 blocks, 8 XCDs -> each XCD owns 2 consecutive bh
    const int swz = (blockIdx.x & 7) * 256 + (blockIdx.x >> 3);
    const int bh = swz >> 7;
    const int qt = swz & 127;
    const int q0 = qt * QT;
    const int b_ = bh >> 2, h_ = bh & 3;

    const size_t fb = (size_t)bh * 16384;     // 16B-unit stride per bh
    const bf16x8* qBv = (const bf16x8*)qB + fb + (size_t)qt * 128;
    const bf16x8* kAv = (const bf16x8*)kA + fb;
    const bf16x8* vBv = (const bf16x8*)vB + fb;

    // mask bits for this wave's 256-col stripe: words w*8..w*8+7
    unsigned mreg[8];
    {
        const unsigned* mwp = mbits + b_ * 64 + w * 8;
        #pragma unroll
        for (int i = 0; i < 8; ++i) mreg[i] = mwp[i];
    }

    bf16x8 qf0 = qBv[lane];
    bf16x8 qf1 = qBv[64 + lane];

    f32x4 acc[16];
    #pragma unroll
    for (int t = 0; t < 16; ++t) acc[t] = (f32x4){0.f, 0.f, 0.f, 0.f};

    #pragma unroll
    for (int t = 0; t < 16; ++t) {
        int kt = w * 16 + t;
        bf16x8 kf0 = kAv[(kt * 2 + 0) * 64 + lane];
        bf16x8 kf1 = kAv[(kt * 2 + 1) * 64 + lane];
        acc[t] = __builtin_amdgcn_mfma_f32_16x16x32_bf16(kf0, qf0, acc[t], 0, 0, 0);
        acc[t] = __builtin_amdgcn_mfma_f32_16x16x32_bf16(kf1, qf1, acc[t], 0, 0, 0);
    }

    // fold mask (bit test), store masked scores bf16 into swizzled LDS
    const short NEGB = (short)0xFF7F;         // bf16 -3.39e38
    char* prow = (char*)S_s + l15 * 4096;
    const int sw = (l15 & 7) << 4;
    #pragma unroll
    for (int t = 0; t < 16; ++t) {
        unsigned bits = mreg[t >> 1] >> (((t & 1) << 4) + (g << 2));
        s16x4 sb;
        sb[0] = (bits & 1) ? f2bs(acc[t][0]) : NEGB;
        sb[1] = (bits & 2) ? f2bs(acc[t][1]) : NEGB;
        sb[2] = (bits & 4) ? f2bs(acc[t][2]) : NEGB;
        sb[3] = (bits & 8) ? f2bs(acc[t][3]) : NEGB;
        *(s16x4*)(prow + ((w * 512 + t * 32 + g * 8) ^ sw)) = sb;
    }
    lds_barrier();

    // ---- phase 2/3 pipelined per row: Michelot(h) then store(h) ----
    const int r0 = 2 * w;
    float va[2][32];
    #pragma unroll
    for (int h = 0; h < 2; ++h) {
        const char* sr = (const char*)S_s + (r0 + h) * 4096;
        int swr = ((r0 + h) & 7) << 4;
        #pragma unroll
        for (int jj = 0; jj < 8; ++jj) {
            s16x4 p4 = *(const s16x4*)(sr + ((jj * 512 + lane * 8) ^ swr));
            va[h][jj * 4 + 0] = b2f(p4[0]);
            va[h][jj * 4 + 1] = b2f(p4[1]);
            va[h][jj * 4 + 2] = b2f(p4[2]);
            va[h][jj * 4 + 3] = b2f(p4[3]);
        }
    }

    #pragma unroll
    for (int h = 0; h < 2; ++h) {
        // --- Michelot for row r0+h ---
        float S = 0.f, C = 0.f, Qs = 0.f;
        #pragma unroll
        for (int i = 0; i < 32; ++i) {
            float v = va[h][i];
            bool un = v > -1.0e30f;
            float sv = un ? v : 0.f;
            S += sv;
            C += un ? 1.f : 0.f;
            Qs = __builtin_fmaf(sv, sv, Qs);
        }
        S = wave_sum(S); C = wave_sum(C); Qs = wave_sum(Qs);
        float tu, prevC;
        bool done;
        if (C < 0.5f) { tu = 3.0e38f; done = true; prevC = 0.f; }
        else {
            float mu = S / C;
            float var = Qs / C - mu * mu;
            var = var > 0.f ? var : 0.f;
            tu = mu + 1.7f * __builtin_sqrtf(var);   // warm start
            prevC = -1.f;
            done = false;
        }
        for (int it = 0; it < 64 && !done; ++it) {
            float S2 = 0.f, C2 = 0.f;
            #pragma unroll
            for (int i = 0; i < 32; ++i) {
                float v = va[h][i];
                bool in = v > tu;
                S2 += in ? v : 0.f;
                C2 += in ? 1.f : 0.f;
            }
            S2 = wave_sum(S2); C2 = wave_sum(C2);
            if (C2 == prevC) done = true;
            else if (C2 < 0.5f) { tu = (S - 1.f) / C; prevC = -1.f; }  // overshoot restart
            else { tu = (S2 - 1.f) / C2; prevC = C2; }
        }
        // --- store row r0+h: attn fp32 (nt, fire-and-forget) + P bf16 to LDS ---
        char* sr = (char*)S_s + (r0 + h) * 4096;
        int swr = ((r0 + h) & 7) << 4;
        float* ar = attn + ((size_t)bh * TT + q0 + r0 + h) * TT;
        #pragma unroll
        for (int jj = 0; jj < 8; ++jj) {
            f32x4 o;
            s16x4 pb4;
            #pragma unroll
            for (int e = 0; e < 4; ++e) {
                float a = va[h][jj * 4 + e] - tu;
                a = a > 0.f ? a : 0.f;
                o[e] = a;
                pb4[e] = f2bs(a);
            }
            __builtin_nontemporal_store(o, (f32x4*)(ar + jj * 256 + lane * 4));
            *(s16x4*)(sr + ((jj * 512 + lane * 8) ^ swr)) = pb4;
        }
    }
    // LDS-only barrier: attn stores stay in flight and drain under PV
    lds_barrier();

    // ---- phase 4: fused PV: wave w -> d-slice ds=(w&3)*16, K-half kh=w>>2 ----
    const int ds = w & 3;
    const int kh = w >> 2;
    f32x4 xacc = (f32x4){0.f, 0.f, 0.f, 0.f};
    __builtin_amdgcn_s_setprio(1);
    #pragma unroll 8
    for (int kcl = 0; kcl < 32; ++kcl) {
        int kc = kh * 32 + kcl;
        bf16x8 af = *(const bf16x8*)(prow + ((kh * 2048 + kcl * 64 + g * 16) ^ sw));
        bf16x8 bfr = vBv[(kc * 4 + ds) * 64 + lane];
        xacc = __builtin_amdgcn_mfma_f32_16x16x32_bf16(af, bfr, xacc, 0, 0, 0);
    }
    __builtin_amdgcn_s_setprio(0);
    if (w >= 4) xpart[w - 4][lane] = make_float4(xacc[0], xacc[1], xacc[2], xacc[3]);
    lds_barrier();
    if (w < 4) {
        float4 xp4 = xpart[w][lane];
        xacc[0] += xp4.x; xacc[1] += xp4.y; xacc[2] += xp4.z; xacc[3] += xp4.w;
        float* xp = xout + ((size_t)b_ * TT + q0 + g * 4) * NF + h_ * DKK + ds * 16 + l15;
        #pragma unroll
        for (int p = 0; p < 4; ++p)
            __builtin_nontemporal_store(xacc[p], xp + p * NF);
    }
}

extern "C" void kernel_launch(void* const* d_in, const int* in_sizes, int n_in,
                              void* d_out, int out_size, void* d_ws, size_t ws_size,
                              hipStream_t stream) {
    const float* query = (const float*)d_in[0];
    const float* key   = (const float*)d_in[1];
    const float* value = (const float*)d_in[2];
    const int*   mask  = (const int*)d_in[3];
    const float* Wq = (const float*)d_in[4];
    const float* bq = (const float*)d_in[5];
    const float* Wk = (const float*)d_in[6];
    const float* bk = (const float*)d_in[7];
    const float* Wv = (const float*)d_in[8];
    const float* bv = (const float*)d_in[9];

    float* attn = (float*)d_out;                                 // (B,H,T,T)
    float* x    = (float*)d_out + (size_t)NB * NH * TT * TT;     // (B,T,NF)

    const size_t FRAG = (size_t)NB * NH * 16384 * 8;             // 2,097,152 bf16 each
    bf16* Wb = (bf16*)d_ws;                  // 384 KB
    bf16* qB = Wb + 3 * 65536;               // 4 MB
    bf16* kA = qB + FRAG;                    // 4 MB
    bf16* vB = kA + FRAG;                    // 4 MB
    unsigned* mbits = (unsigned*)(vB + FRAG);// 1 KB

    wcvt_kernel<<<dim3(193), dim3(256), 0, stream>>>(Wq, Wk, Wv, mask, Wb, mbits);
    qkv_kernel<<<dim3(NB * TT / 16), dim3(256), 0, stream>>>(
        query, key, value, Wb, bq, bk, bv, qB, kA, vB);
    attn_kernel<<<dim3(NB * NH * (TT / QT)), dim3(512), 0, stream>>>(
        qB, kA, vB, mbits, attn, x);
}